// Round 18
// baseline (98.665 us; speedup 1.0000x reference)
//
#include <hip/hip_runtime.h>

typedef unsigned int u32;

// ---------------- FFT-based reverb (R17: slim LDS -> 4 blocks/CU) ----------------
// Math identical to R16 (validated): four-step T1 (M=1024x1024), pointwise,
// half-size real IFFT for T2' (N2=2^19 = 512x1024), fused kBC.
// R17: lt2 table removed from LDS (epilogue twiddles read from constexpr ROM,
// L1-cached); lt1 halved to 512 entries (stage indices provably <= 510).
// LDS/block: 34816 (bufs) + 4096 (lt1) = 38912 B -> 4 blocks/CU (was 3).

constexpr int N_AUDIO = 480000;
constexpr int M_FFT   = 1048576;      // 2^20

constexpr size_t OFF_C0   = 0;                    // 8 MB float2
constexpr size_t OFF_C1   = (size_t)M_FFT * 8;    // 8 MB float2
constexpr size_t OFF_SLOT = OFF_C1 + (size_t)M_FFT * 8;   // u32

#define SW(i) ((i) + ((i) >> 4))      // LDS pad swizzle
constexpr int LSZ = 1088;             // SW(1023)=1086

// ---- compile-time twiddle ROM (constexpr Taylor, double precision) ----
struct F2 { float x, y; };
constexpr double D_PI = 3.14159265358979323846264338327950288;
constexpr double tay_sin(double x) {
    double t = x, s = x, x2 = x * x;
    for (int k = 1; k <= 11; ++k) { t *= -x2 / (double)((2 * k) * (2 * k + 1)); s += t; }
    return s;
}
constexpr double tay_cos(double x) {
    double t = 1.0, s = 1.0, x2 = x * x;
    for (int k = 1; k <= 11; ++k) { t *= -x2 / (double)((2 * k - 1) * (2 * k)); s += t; }
    return s;
}
struct Tab { F2 v[1024]; };
constexpr Tab make_t1() {   // W_1024^j, arg centered to [-pi,pi)
    Tab tb{};
    for (int j = 0; j < 1024; ++j) {
        int jj = (j < 512) ? j : j - 1024;
        double a = -2.0 * D_PI * (double)jj / 1024.0;
        tb.v[j] = F2{(float)tay_cos(a), (float)tay_sin(a)};
    }
    return tb;
}
constexpr Tab make_t2() {   // W_M^j
    Tab tb{};
    for (int j = 0; j < 1024; ++j) {
        double a = -2.0 * D_PI * (double)j / 1048576.0;
        tb.v[j] = F2{(float)tay_cos(a), (float)tay_sin(a)};
    }
    return tb;
}
__device__ constexpr Tab ROM_T1 = make_t1();
__device__ constexpr Tab ROM_T2 = make_t2();

__device__ __forceinline__ float2 ldrom(const Tab& tb, int i) {
    F2 f = tb.v[i];
    return make_float2(f.x, f.y);
}
__device__ __forceinline__ float2 cmul(float2 a, float2 b) {
    return make_float2(a.x * b.x - a.y * b.y, a.x * b.y + a.y * b.x);
}
// W_M^e for e < 2^20, from ROM (global, L1-cached)
__device__ __forceinline__ float2 wM(int e) {
    return cmul(ldrom(ROM_T1, e >> 10), ldrom(ROM_T2, e & 1023));
}
// stage lt1: 512 entries (stage twiddle indices are <= 510)
__device__ __forceinline__ void stage_lt1(float2* lt1, int t) {
    #pragma unroll
    for (int q = 0; q < 2; ++q) { int i = t + 256 * q; lt1[i] = ldrom(ROM_T1, i); }
}

// Radix-4 Stockham FFT-1024, 2 rows, 256 threads, 5 stages, result in B0. (validated)
__device__ __forceinline__ void fft1024_r4(float2 (*A0)[LSZ], float2 (*B0)[LSZ],
                                           const float2* lt1, int t) {
    float2 (*A)[LSZ] = A0;
    float2 (*B)[LSZ] = B0;
    #pragma unroll
    for (int s = 0; s < 5; ++s) {
        const int L  = 1 << (2 * s);
        const int k  = t & (L - 1);
        const int p0 = 4 * t - 3 * k;
        const float2 w  = lt1[k << (9 - 2 * s)];   // e^{-2pi i k/(2L)}, idx <= 510
        const float2 w2 = lt1[k << (8 - 2 * s)];   // e^{-2pi i k/(4L)}, idx <= 255
        #pragma unroll
        for (int j = 0; j < 2; ++j) {
            float2 x0 = A[j][SW(t)];
            float2 x2 = A[j][SW(t + 256)];
            float2 x1 = A[j][SW(t + 512)];
            float2 x3 = A[j][SW(t + 768)];
            float2 wx1 = cmul(w, x1), wx3 = cmul(w, x3);
            float2 u0 = make_float2(x0.x + wx1.x, x0.y + wx1.y);
            float2 u1 = make_float2(x0.x - wx1.x, x0.y - wx1.y);
            float2 u2 = make_float2(x2.x + wx3.x, x2.y + wx3.y);
            float2 u3 = make_float2(x2.x - wx3.x, x2.y - wx3.y);
            float2 a2 = cmul(w2, u2);
            float2 a3 = cmul(w2, u3);
            B[j][SW(p0)]         = make_float2(u0.x + a2.x, u0.y + a2.y);
            B[j][SW(p0 + L)]     = make_float2(u1.x + a3.y, u1.y - a3.x); // u1 - i*a3
            B[j][SW(p0 + 2*L)]   = make_float2(u0.x - a2.x, u0.y - a2.y);
            B[j][SW(p0 + 3*L)]   = make_float2(u1.x - a3.y, u1.y + a3.x); // u1 + i*a3
        }
        __syncthreads();
        float2 (*tmp)[LSZ] = A; A = B; B = tmp;
    }
}

// Radix-4x4 + radix-2 Stockham FFT-512 on TWO independent 512-pt arrays. (validated R16)
__device__ __forceinline__ void fft512_r4(float2 (*A0)[LSZ], float2 (*B0)[LSZ],
                                          const float2* lt1, int t) {
    float2 (*A)[LSZ] = A0;
    float2 (*B)[LSZ] = B0;
    const int j  = t >> 7;
    const int tt = t & 127;
    #pragma unroll
    for (int s = 0; s < 4; ++s) {
        const int L  = 1 << (2 * s);
        const int k  = tt & (L - 1);
        const int p0 = 4 * tt - 3 * k;
        const float2 w  = lt1[k << (9 - 2 * s)];
        const float2 w2 = lt1[k << (8 - 2 * s)];
        float2 x0 = A[j][SW(tt)];
        float2 x2 = A[j][SW(tt + 128)];
        float2 x1 = A[j][SW(tt + 256)];
        float2 x3 = A[j][SW(tt + 384)];
        float2 wx1 = cmul(w, x1), wx3 = cmul(w, x3);
        float2 u0 = make_float2(x0.x + wx1.x, x0.y + wx1.y);
        float2 u1 = make_float2(x0.x - wx1.x, x0.y - wx1.y);
        float2 u2 = make_float2(x2.x + wx3.x, x2.y + wx3.y);
        float2 u3 = make_float2(x2.x - wx3.x, x2.y - wx3.y);
        float2 a2 = cmul(w2, u2);
        float2 a3 = cmul(w2, u3);
        B[j][SW(p0)]       = make_float2(u0.x + a2.x, u0.y + a2.y);
        B[j][SW(p0 + L)]   = make_float2(u1.x + a3.y, u1.y - a3.x);
        B[j][SW(p0 + 2*L)] = make_float2(u0.x - a2.x, u0.y - a2.y);
        B[j][SW(p0 + 3*L)] = make_float2(u1.x - a3.y, u1.y + a3.x);
        __syncthreads();
        float2 (*tmp)[LSZ] = A; A = B; B = tmp;
    }
    #pragma unroll
    for (int h = 0; h < 2; ++h) {
        int i = tt + 128 * h;                   // 0..255
        float2 x0 = A[j][SW(i)];
        float2 x1 = A[j][SW(i + 256)];
        float2 w  = lt1[i << 1];                // idx <= 510
        float2 wx = cmul(w, x1);
        B[j][SW(i)]       = make_float2(x0.x + wx.x, x0.y + wx.y);
        B[j][SW(i + 256)] = make_float2(x0.x - wx.x, x0.y - wx.y);
    }
    __syncthreads();
}

// ---- kernel A: transform-1 pass1 + input pack. 2 rows/block, grid 512.
__global__ __launch_bounds__(256) void kA(const float* __restrict__ a,
                                          const float* __restrict__ b,
                                          float2* __restrict__ outb,
                                          u32* __restrict__ slot) {
    __shared__ float2 buf0[2][LSZ], buf1[2][LSZ], lt1[512];
    const int t  = threadIdx.x;
    const int r0 = blockIdx.x * 2;
    if (blockIdx.x == 0 && t == 0) *slot = 0u;
    stage_lt1(lt1, t);
    #pragma unroll
    for (int q = 0; q < 4; ++q) {
        int c = t + 256 * q;
        int base = c * 1024 + r0;
        float2 av = make_float2(0.f, 0.f), bv = make_float2(0.f, 0.f);
        if (c < 468 || (c == 468 && r0 < 768)) av = *(const float2*)(a + base);
        if (c < 234 || (c == 234 && r0 < 384)) bv = *(const float2*)(b + base);
        buf0[0][SW(c)] = make_float2(av.x, bv.x);
        buf0[1][SW(c)] = make_float2(av.y, bv.y);
    }
    __syncthreads();
    fft1024_r4(buf0, buf1, lt1, t);
    #pragma unroll
    for (int q = 0; q < 4; ++q) {
        int k1 = t + 256 * q;
        #pragma unroll
        for (int j = 0; j < 2; ++j) {
            int e = (r0 + j) * k1;                        // < 2^20
            outb[(r0 + j) * 1024 + k1] = cmul(wM(e), buf1[j][SW(k1)]);
        }
    }
}

// ---- kernel BC: T1 pass2 + pointwise + real-IFFT pack + T2' pass1 (FFT_512). grid 512.
__global__ __launch_bounds__(256) void kBC(const float2* __restrict__ in,
                                           float2* __restrict__ gbuf) {
    __shared__ float2 buf0[2][LSZ], buf1[2][LSZ], lt1[512];
    const int t = threadIdx.x;
    const int bidx = blockIdx.x;
    const int cA = (bidx == 0) ? 0   : bidx;
    const int cB = (bidx == 0) ? 512 : 1024 - bidx;
    stage_lt1(lt1, t);
    #pragma unroll
    for (int q = 0; q < 4; ++q) {
        int r = t + 256 * q;
        buf0[0][SW(r)] = in[r * 1024 + cA];
        buf0[1][SW(r)] = in[r * 1024 + cB];
    }
    __syncthreads();
    fft1024_r4(buf0, buf1, lt1, t);                       // Z1 cols in buf1
    // pointwise: X = A*conj(B) into buf0
    #pragma unroll
    for (int q = 0; q < 4; ++q) {
        int k2 = t + 256 * q;
        #pragma unroll
        for (int j = 0; j < 2; ++j) {
            float2 z1 = buf1[j][SW(k2)];
            float2 z2;
            if (bidx == 0) z2 = (j == 0) ? buf1[0][SW((1024 - k2) & 1023)]
                                         : buf1[1][SW(1023 - k2)];
            else           z2 = buf1[j ^ 1][SW(1023 - k2)];
            float2 Af  = make_float2(0.5f * (z1.x + z2.x), 0.5f * (z1.y - z2.y));
            float2 cBf = make_float2(0.5f * (z1.y + z2.y), 0.5f * (z1.x - z2.x));
            buf0[j][SW(k2)] = cmul(Af, cBf);              // X
        }
    }
    __syncthreads();
    // real-IFFT pack: q[k] = conj(Z[k])/N2 into buf1[j][0..511]
    const float invN2 = 1.0f / 524288.0f;
    #pragma unroll
    for (int j = 0; j < 2; ++j) {
        const int bcol = (j == 0) ? cA : cB;
        const float2 wb = ldrom(ROM_T2, bcol);            // W_M^{bcol}
        #pragma unroll
        for (int h = 0; h < 2; ++h) {
            int k2v = t + 256 * h;                        // 0..511
            float2 z1 = buf0[j][SW(k2v)];                 // X[k]
            int jr, p2;
            if (bidx == 0) { jr = j; p2 = (j == 0) ? (512 - k2v) : (511 - k2v); }
            else           { jr = j ^ 1; p2 = 511 - k2v; }
            float2 z2c = buf0[jr][SW(p2)];                // X[N2-k]
            z2c.y = -z2c.y;                               // conj
            float2 A2 = make_float2(0.5f * (z1.x + z2c.x), 0.5f * (z1.y + z2c.y));
            float2 D2 = make_float2(0.5f * (z1.x - z2c.x), 0.5f * (z1.y - z2c.y));
            float2 cw = cmul(ldrom(ROM_T1, k2v), wb);     // W_M^k
            float2 iB = cmul(make_float2(cw.y, cw.x), D2);// i*conj(cw)*D
            float2 Z  = make_float2(A2.x + iB.x, A2.y + iB.y);
            buf1[j][SW(k2v)] = make_float2(Z.x * invN2, -Z.y * invN2);  // conj(Z)/N2
        }
    }
    __syncthreads();
    fft512_r4(buf1, buf0, lt1, t);                        // G in buf0[j][0..511]
    const int jc = t >> 7, tt = t & 127;
    const int bcol = (jc == 0) ? cA : cB;
    #pragma unroll
    for (int u = 0; u < 4; ++u) {
        int k1 = tt + 128 * u;                            // 0..511
        int e2 = 2 * bcol * k1;                           // <= 1045506
        gbuf[bcol * 512 + k1] = cmul(wM(e2 & 1048575), buf0[jc][SW(k1)]);
    }
}

// ---- kernel D: T2' pass2 (FFT_1024 over b), k1' pair {2q,2q+1}. grid 256.
__global__ __launch_bounds__(256) void kD(const float2* __restrict__ gbuf,
                                          float2* __restrict__ rawT2,
                                          u32* __restrict__ slot) {
    __shared__ float2 buf0[2][LSZ], buf1[2][LSZ], lt1[512];
    __shared__ float wmax[4];
    const int t = threadIdx.x;
    const int qb = blockIdx.x;                            // k1' = 2qb, 2qb+1
    stage_lt1(lt1, t);
    #pragma unroll
    for (int q = 0; q < 4; ++q) {
        int b = t + 256 * q;
        float4 v = *(const float4*)(gbuf + (size_t)b * 512 + 2 * qb);
        buf0[0][SW(b)] = make_float2(v.x, v.y);
        buf0[1][SW(b)] = make_float2(v.z, v.w);
    }
    __syncthreads();
    fft1024_r4(buf0, buf1, lt1, t);                       // W' in buf1
    float m = 0.0f;
    #pragma unroll
    for (int q = 0; q < 4; ++q) {
        int k2 = t + 256 * q;
        #pragma unroll
        for (int j = 0; j < 2; ++j) {
            int k1 = 2 * qb + j;
            int to = 2 * k1 + 1024 * k2;                  // even output index
            if (to < N_AUDIO) {
                float2 v = buf1[j][SW(k2)];
                rawT2[k1 * 1024 + k2] = make_float2(v.x, -v.y);
                m = fmaxf(m, fmaxf(fabsf(v.x), fabsf(v.y)));
            }
        }
    }
    for (int off = 32; off > 0; off >>= 1) m = fmaxf(m, __shfl_down(m, off, 64));
    if ((t & 63) == 0) wmax[t >> 6] = m;
    __syncthreads();
    if (t == 0) {
        float bm = fmaxf(fmaxf(wmax[0], wmax[1]), fmaxf(wmax[2], wmax[3]));
        atomicMax(slot, __float_as_uint(bm));
    }
}

// ---- kernel E: tiled transpose (512 x 1024 float2) + normalize. grid 128.
__global__ __launch_bounds__(256) void kE(const float2* __restrict__ rawT2,
                                          const u32* __restrict__ slot,
                                          float* __restrict__ out) {
    __shared__ float2 tile[64][65];
    const int t  = threadIdx.x;
    const int K0 = (blockIdx.x & 7) * 64;         // k1' tile (8)
    const int Q0 = (blockIdx.x >> 3) * 64;        // k2' tile (16)
    #pragma unroll
    for (int i = 0; i < 16; ++i) {
        int idx = t + 256 * i;
        int row = idx >> 6, col = idx & 63;
        tile[col][row] = rawT2[(size_t)(K0 + row) * 1024 + Q0 + col];
    }
    __syncthreads();
    const float inv = 1.0f / __uint_as_float(*slot);
    #pragma unroll
    for (int i = 0; i < 16; ++i) {
        int idx = t + 256 * i;
        int cc = idx >> 6, rr = idx & 63;
        int o = (Q0 + cc) * 1024 + 2 * (K0 + rr);
        if (o < N_AUDIO) {
            float2 v = tile[cc][rr];
            *(float2*)(out + o) = make_float2(v.x * inv, v.y * inv);
        }
    }
}

extern "C" void kernel_launch(void* const* d_in, const int* in_sizes, int n_in,
                              void* d_out, int out_size, void* d_ws, size_t ws_size,
                              hipStream_t stream) {
    const float* audio = (const float*)d_in[0];
    const float* ir    = (const float*)d_in[1];
    float* out = (float*)d_out;

    char* ws = (char*)d_ws;
    float2* cb0 = (float2*)(ws + OFF_C0);
    float2* cb1 = (float2*)(ws + OFF_C1);
    u32*    slot = (u32*)(ws + OFF_SLOT);

    kA<<<512, 256, 0, stream>>>(audio, ir, cb1, slot);          // pack + T1 rows
    kBC<<<512, 256, 0, stream>>>(cb1, cb0);                     // T1 cols + pw + pack + T2' rows
    kD<<<256, 256, 0, stream>>>(cb0, cb1, slot);                // T2' cols + absmax -> rawT2
    kE<<<128, 256, 0, stream>>>((const float2*)cb1, slot, out); // transpose + scale
}